// Round 8
// baseline (384.522 us; speedup 1.0000x reference)
//
#include <hip/hip_runtime.h>

// GridManifoldNetwork, round 21 = R20 + complete nontemporal hygiene.
// Wall model (R13-R20): random gathers run at ~0.232M lane-req/us chip-wide
// while tables are per-XCD-L2 resident; misses refetch 64B lines. R20's
// fused (pk5 2MB + A2/B2 2MB = 4MB) missed its 108us wall prediction by
// ~70us with FETCH 234MB; identified polluter: LDS staging read `packed[t]`
// with PLAIN CACHED loads = 75MB streaming through L2 evicting the tables
// (same bug in K1's tail: ~8MB cached grid stream vs hash3's table).
// R21 fixes only that: NT loads for staging + tail streams, NT stores for
// packed/A2/B2/pk5. No structural change vs R20.
//
// Predicted: fused 178 -> 115-135us, FETCH < 160MB (decisive), total
// ~265-285us. Falsifier: fused >=160us or FETCH >=200MB -> co-residency
// impossible -> revert to R18 split (308us) and argue roofline.
//
// Kept verbatim (proven): R13 hash gather form (hash3/hash4, fp32 tables),
// R11 MLP form, 144KB LDS levels 0+1, A2/B2 level-2 pair tables, prep-in-
// tail pattern (128 tail blocks absorb pk5/A2/B2/packed01/wt).
//
// Levels: res=16,32,64,128,256,512; F=2; T=2^19; levels 3..5 hashed,
// & 0x7FFFF. Entry offsets: 0,4096,36864,299008,823296,1347584.

#define HP1 2654435761u
#define HP2 805459861u
#define HMASK ((1u << 19) - 1u)

typedef float v2f __attribute__((ext_vector_type(2)));

static __device__ __forceinline__ unsigned umin_(unsigned a, unsigned b) {
    return a < b ? a : b;
}

// bf16 round-to-nearest-even pack/unpack.
static __device__ __forceinline__ unsigned f2bf(float f) {
    unsigned u = __float_as_uint(f);
    return (u + 0x7fffu + ((u >> 16) & 1u)) >> 16;
}
static __device__ __forceinline__ float bf2f_lo(unsigned p) {
    return __uint_as_float((p & 0xffffu) << 16);
}
static __device__ __forceinline__ float bf2f_hi(unsigned p) {
    return __uint_as_float(p & 0xffff0000u);
}

static __device__ __forceinline__ v2f vmax0(v2f s) {
#if __has_builtin(__builtin_elementwise_max)
    return __builtin_elementwise_max(s, (v2f)0.0f);
#else
    v2f r; r.x = fmaxf(s.x, 0.0f); r.y = fmaxf(s.y, 0.0f); return r;
#endif
}

// NT read of a float2 as two floats (builtin needs scalar types).
static __device__ __forceinline__ void nt_load_f2(
    const float2* __restrict__ p, float& ex, float& ey)
{
    const unsigned long long u =
        __builtin_nontemporal_load((const unsigned long long*)p);
    ex = __uint_as_float((unsigned)u);
    ey = __uint_as_float((unsigned)(u >> 32));
}

// One hashed-level point block: R13 form verbatim. 8 divergent 8B gathers
// from the fp32 float2 table + trilerp + bf16 pack. 72.5us/level proven.
static __device__ __forceinline__ void hash_body(
    const float* __restrict__ x, const float2* __restrict__ tab,
    unsigned* __restrict__ feat, float scale, int N, int bid)
{
    const int gid = bid * 256 + threadIdx.x;
    if (gid >= N) return;

    const float px = __builtin_nontemporal_load(x + 3 * gid + 0);
    const float py = __builtin_nontemporal_load(x + 3 * gid + 1);
    const float pz = __builtin_nontemporal_load(x + 3 * gid + 2);

    const float p0 = fmaf((px + 1.0f) * 0.5f, scale, 0.5f);
    const float p1 = fmaf((py + 1.0f) * 0.5f, scale, 0.5f);
    const float p2 = fmaf((pz + 1.0f) * 0.5f, scale, 0.5f);
    const float g0 = floorf(p0), g1 = floorf(p1), g2 = floorf(p2);
    const float f0 = p0 - g0, f1 = p1 - g1, f2 = p2 - g2;
    const unsigned i0 = (unsigned)g0, i1 = (unsigned)g1, i2 = (unsigned)g2;

    const float wx[2] = {1.0f - f0, f0};
    const float wy[2] = {1.0f - f1, f1};
    const float wz[2] = {1.0f - f2, f2};
    const unsigned hx[2] = {i0, i0 + 1u};
    const unsigned hy[2] = {i1 * HP1, (i1 + 1u) * HP1};
    const unsigned hz[2] = {i2 * HP2, (i2 + 1u) * HP2};

    unsigned idx[8];
    float w[8];
    #pragma unroll
    for (int c = 0; c < 8; ++c) {
        const int bx = c & 1, by = (c >> 1) & 1, bz = (c >> 2) & 1;
        idx[c] = (hx[bx] ^ hy[by] ^ hz[bz]) & HMASK;
        w[c] = wx[bx] * wy[by] * wz[bz];
    }
    float2 v[8];
    #pragma unroll
    for (int c = 0; c < 8; ++c) v[c] = tab[idx[c]];

    float a0 = 0.0f, a1 = 0.0f;
    #pragma unroll
    for (int c = 0; c < 8; ++c) {
        a0 = fmaf(w[c], v[c].x, a0);
        a1 = fmaf(w[c], v[c].y, a1);
    }
    __builtin_nontemporal_store(f2bf(a0) | (f2bf(a1) << 16), feat + gid);
}

// Hash level 3 + all prep folded into 128 tail blocks. Tail streams are
// fully nontemporal (reads AND writes) so they never evict hash3's table.
__global__ __launch_bounds__(256) void hash3_prep_kernel(
    const float* __restrict__ x, const float2* __restrict__ gtab,
    unsigned* __restrict__ feat0, int N,
    float* __restrict__ wt, unsigned* __restrict__ packed,
    unsigned* __restrict__ A2, unsigned* __restrict__ B2,
    unsigned* __restrict__ pk5,
    const float* __restrict__ W0, const float* __restrict__ b0,
    const float* __restrict__ W1, const float* __restrict__ b1)
{
    const int nh = (int)gridDim.x - 128;
    if ((int)blockIdx.x >= nh) {
        const int pb = (int)blockIdx.x - nh;   // 0..127
        const int stride = 128 * 256;
        for (int t = pb * 256 + threadIdx.x; t < 36864; t += stride) {
            float ex, ey;
            nt_load_f2(gtab + t, ex, ey);
            __builtin_nontemporal_store(f2bf(ex) | (f2bf(ey) << 16),
                                        packed + t);
        }
        const float2* g2 = gtab + 36864u;      // level 2, 64^3 entries
        for (int t = pb * 256 + threadIdx.x; t < 262144; t += stride) {
            float ex, ey;
            nt_load_f2(g2 + t, ex, ey);
            __builtin_nontemporal_store(f2bf(ex) | (f2bf(ey) << 16), A2 + t);
            const int xc = t & 63;
            float nx, ny;
            nt_load_f2(g2 + ((xc == 63) ? t : t + 1), nx, ny);
            __builtin_nontemporal_store(f2bf(nx) | (f2bf(ny) << 16), B2 + t);
        }
        const float2* g5 = gtab + 1347584u;    // hash level 5
        for (int t = pb * 256 + threadIdx.x; t < 524288; t += stride) {
            float ex, ey;
            nt_load_f2(g5 + t, ex, ey);
            __builtin_nontemporal_store(f2bf(ex) | (f2bf(ey) << 16), pk5 + t);
        }
        if (pb == 0) {
            for (int t = threadIdx.x; t < 1024; t += 256) {
                const int j = t >> 4, i = t & 15;
                wt[t] = (i == 15) ? b0[j] : W0[i * 64 + j];
            }
            if (threadIdx.x < 64) wt[1024 + threadIdx.x] = W1[threadIdx.x];
            if (threadIdx.x == 0) wt[1088] = b1[0];
        }
        return;
    }
    hash_body(x, gtab + 299008u, feat0, 127.0f, N, (int)blockIdx.x);
}

__global__ __launch_bounds__(256) void hash_level_kernel(
    const float* __restrict__ x, const float2* __restrict__ tab,
    unsigned* __restrict__ feat, float scale, int N)
{
    hash_body(x, tab, feat, scale, N, (int)blockIdx.x);
}

// Dense trilinear level from global fp32 float2 (level-1 fallback only).
static __device__ __forceinline__ void dense_level(
    const float2* __restrict__ tab, unsigned res,
    float xn0, float xn1, float xn2, float& o0, float& o1)
{
    const float scale = (float)(res - 1);
    const float p0 = fmaf(xn0, scale, 0.5f);
    const float p1 = fmaf(xn1, scale, 0.5f);
    const float p2 = fmaf(xn2, scale, 0.5f);
    const float g0 = floorf(p0), g1 = floorf(p1), g2 = floorf(p2);
    const float f0 = p0 - g0, f1 = p1 - g1, f2 = p2 - g2;
    const unsigned i0 = (unsigned)g0, i1 = (unsigned)g1, i2 = (unsigned)g2;

    const unsigned rm1 = res - 1u;
    const unsigned cx[2] = {umin_(i0, rm1), umin_(i0 + 1u, rm1)};
    const unsigned cy[2] = {umin_(i1, rm1) * res, umin_(i1 + 1u, rm1) * res};
    const unsigned cz[2] = {umin_(i2, rm1) * res * res,
                            umin_(i2 + 1u, rm1) * res * res};
    const float wx[2] = {1.0f - f0, f0};
    const float wy[2] = {1.0f - f1, f1};
    const float wz[2] = {1.0f - f2, f2};

    float a0 = 0.0f, a1 = 0.0f;
    #pragma unroll
    for (int c = 0; c < 8; ++c) {
        const int bx = c & 1, by = (c >> 1) & 1, bz = (c >> 2) & 1;
        const unsigned idx = cx[bx] + cy[by] + cz[bz];
        const float w = wx[bx] * wy[by] * wz[bz];
        const float2 v = tab[idx];
        a0 = fmaf(w, v.x, a0);
        a1 = fmaf(w, v.y, a1);
    }
    o0 = a0;
    o1 = a1;
}

// Dense trilinear level from LDS-resident packed bf16x2 table (R11 form).
static __device__ __forceinline__ void dense_level_lds(
    const unsigned* __restrict__ sPk, unsigned off, unsigned res,
    float xn0, float xn1, float xn2, float& o0, float& o1)
{
    const float scale = (float)(res - 1);
    const float p0 = fmaf(xn0, scale, 0.5f);
    const float p1 = fmaf(xn1, scale, 0.5f);
    const float p2 = fmaf(xn2, scale, 0.5f);
    const float g0 = floorf(p0), g1 = floorf(p1), g2 = floorf(p2);
    const float f0 = p0 - g0, f1 = p1 - g1, f2 = p2 - g2;
    const unsigned i0 = (unsigned)g0, i1 = (unsigned)g1, i2 = (unsigned)g2;

    const unsigned rm1 = res - 1u;
    const unsigned cx[2] = {umin_(i0, rm1), umin_(i0 + 1u, rm1)};
    const unsigned cy[2] = {umin_(i1, rm1) * res, umin_(i1 + 1u, rm1) * res};
    const unsigned cz[2] = {umin_(i2, rm1) * res * res,
                            umin_(i2 + 1u, rm1) * res * res};
    const float wx[2] = {1.0f - f0, f0};
    const float wy[2] = {1.0f - f1, f1};
    const float wz[2] = {1.0f - f2, f2};

    float a0 = 0.0f, a1 = 0.0f;
    #pragma unroll
    for (int c = 0; c < 8; ++c) {
        const int bx = c & 1, by = (c >> 1) & 1, bz = (c >> 2) & 1;
        const unsigned p = sPk[off + cx[bx] + cy[by] + cz[bz]];
        const float w = wx[bx] * wy[by] * wz[bz];
        a0 = fmaf(w, bf2f_lo(p), a0);
        a1 = fmaf(w, bf2f_hi(p), a1);
    }
    o0 = a0;
    o1 = a1;
}

// Dense level 2 (res=64) from packed pair tables (R15-verified dense win).
static __device__ __forceinline__ void dense_level2_pk(
    const unsigned* __restrict__ A2, const unsigned* __restrict__ B2,
    float xn0, float xn1, float xn2, float& o0, float& o1)
{
    const float p0 = fmaf(xn0, 63.0f, 0.5f);
    const float p1 = fmaf(xn1, 63.0f, 0.5f);
    const float p2 = fmaf(xn2, 63.0f, 0.5f);
    const float g0 = floorf(p0), g1 = floorf(p1), g2 = floorf(p2);
    const float f0 = p0 - g0, f1 = p1 - g1, f2 = p2 - g2;
    const unsigned i0 = (unsigned)g0, i1 = (unsigned)g1, i2 = (unsigned)g2;

    const unsigned cx0 = umin_(i0, 63u);
    const unsigned cy[2] = {umin_(i1, 63u) * 64u, umin_(i1 + 1u, 63u) * 64u};
    const unsigned cz[2] = {umin_(i2, 63u) * 4096u,
                            umin_(i2 + 1u, 63u) * 4096u};
    const float wx[2] = {1.0f - f0, f0};
    const float wy[2] = {1.0f - f1, f1};
    const float wz[2] = {1.0f - f2, f2};

    const unsigned* tsel = (cx0 & 1u) ? B2 : A2;
    const unsigned xb = cx0 & ~1u;

    float a0 = 0.0f, a1 = 0.0f;
    #pragma unroll
    for (int c = 0; c < 4; ++c) {
        const int by = c & 1, bz = (c >> 1) & 1;
        const uint2 q = *reinterpret_cast<const uint2*>(
            tsel + xb + cy[by] + cz[bz]);
        const float wyz = wy[by] * wz[bz];
        const float w0 = wyz * wx[0], w1 = wyz * wx[1];
        a0 = fmaf(w0, bf2f_lo(q.x), a0);
        a1 = fmaf(w0, bf2f_hi(q.x), a1);
        a0 = fmaf(w1, bf2f_lo(q.y), a0);
        a1 = fmaf(w1, bf2f_hi(q.y), a1);
    }
    o0 = a0;
    o1 = a1;
}

// Hash level 5 inline from bf16x2 packed table (4B gathers, 2MB resident).
static __device__ __forceinline__ void hash5_pt(
    const unsigned* __restrict__ tab, float xn0, float xn1, float xn2,
    float& o0, float& o1)
{
    const float p0 = fmaf(xn0, 511.0f, 0.5f);
    const float p1 = fmaf(xn1, 511.0f, 0.5f);
    const float p2 = fmaf(xn2, 511.0f, 0.5f);
    const float g0 = floorf(p0), g1 = floorf(p1), g2 = floorf(p2);
    const float f0 = p0 - g0, f1 = p1 - g1, f2 = p2 - g2;
    const unsigned i0 = (unsigned)g0, i1 = (unsigned)g1, i2 = (unsigned)g2;

    const float wx[2] = {1.0f - f0, f0};
    const float wy[2] = {1.0f - f1, f1};
    const float wz[2] = {1.0f - f2, f2};
    const unsigned hx[2] = {i0, i0 + 1u};
    const unsigned hy[2] = {i1 * HP1, (i1 + 1u) * HP1};
    const unsigned hz[2] = {i2 * HP2, (i2 + 1u) * HP2};

    unsigned idx[8];
    float w[8];
    #pragma unroll
    for (int c = 0; c < 8; ++c) {
        const int bx = c & 1, by = (c >> 1) & 1, bz = (c >> 2) & 1;
        idx[c] = (hx[bx] ^ hy[by] ^ hz[bz]) & HMASK;
        w[c] = wx[bx] * wy[by] * wz[bz];
    }
    unsigned v[8];
    #pragma unroll
    for (int c = 0; c < 8; ++c) v[c] = tab[idx[c]];

    float a0 = 0.0f, a1 = 0.0f;
    #pragma unroll
    for (int c = 0; c < 8; ++c) {
        a0 = fmaf(w[c], bf2f_lo(v[c]), a0);
        a1 = fmaf(w[c], bf2f_hi(v[c]), a1);
    }
    o0 = a0;
    o1 = a1;
}

// MLP for one 2-point pair: R11 form verbatim (weights via SMEM pipe,
// v_pk_fma over v2f pairs).
static __device__ __forceinline__ v2f mlp_pair(
    const float* __restrict__ wt, const v2f* __restrict__ hp)
{
    v2f o2 = (v2f)wt[1088];
    #pragma unroll 4
    for (int j = 0; j < 64; ++j) {
        float r[16];
        #pragma unroll
        for (int i = 0; i < 16; ++i)
            r[i] = wt[j * 16 + i];          // uniform -> s_load (SMEM pipe)
        const float w1j = wt[1024 + j];
        v2f s = (v2f)0.0f;
        #pragma unroll
        for (int i = 0; i < 16; ++i)
            s = hp[i] * r[i] + s;            // v_pk_fma_f32
        s = vmax0(s);
        o2 = s * w1j + o2;
    }
    return o2;
}

// FUSED K3: hash level 5 (bf16 table) + dense levels 0/1/2 + MLP,
// 4 points/thread. 12 random req/pt over 4MB resident tables; ALL stream
// traffic (x, feat, staging, out) nontemporal so tables stay resident.
template<int BLOCK, bool L1LDS>
__global__ __launch_bounds__(BLOCK, 4) void fused5_mlp_kernel(
    const float* __restrict__ x,
    const float* __restrict__ grid,
    const unsigned* __restrict__ feat,   // [2][N] packed bf16x2 (lvl 3,4)
    const float* __restrict__ wt,        // 1089 floats
    const unsigned* __restrict__ packed, // 36864 bf16x2 words (levels 0+1)
    const unsigned* __restrict__ A2,     // level-2 packed (identity)
    const unsigned* __restrict__ B2,     // level-2 packed (x+1, clamped)
    const unsigned* __restrict__ pk5,    // hash level 5, bf16x2 (2MB)
    float* __restrict__ out, int N)
{
    extern __shared__ unsigned sPk[];
    const int tid = threadIdx.x;

    const int nstage = L1LDS ? 36864 : 4096;
    for (int t = tid; t < nstage; t += BLOCK)
        sPk[t] = __builtin_nontemporal_load(packed + t);   // NT: no L2 evict
    __syncthreads();

    const int base = blockIdx.x * (BLOCK * 4) + tid;
    const float2* gtab = (const float2*)grid;

    // hp[p][i] = {feature i of point 2p, feature i of point 2p+1}
    v2f hp[2][16];

    #pragma unroll
    for (int k = 0; k < 4; ++k) {
        const int g = base + BLOCK * k;
        const int gs = (g < N) ? g : 0;
        const int p = k >> 1, lane = k & 1;

        const float px = __builtin_nontemporal_load(x + 3 * gs + 0);
        const float py = __builtin_nontemporal_load(x + 3 * gs + 1);
        const float pz = __builtin_nontemporal_load(x + 3 * gs + 2);
        const float xn0 = (px + 1.0f) * 0.5f;
        const float xn1 = (py + 1.0f) * 0.5f;
        const float xn2 = (pz + 1.0f) * 0.5f;

        hp[p][0][lane] = px; hp[p][1][lane] = py; hp[p][2][lane] = pz;
        hp[p][15][lane] = 1.0f;

        // Hash level 5 inline (bf16 table, no feat2 round-trip).
        float h5a, h5b;
        hash5_pt(pk5, xn0, xn1, xn2, h5a, h5b);
        hp[p][13][lane] = h5a; hp[p][14][lane] = h5b;

        // Dense levels 0..2.
        float t3, t4, t5, t6, t7, t8;
        dense_level_lds(sPk, 0u, 16u, xn0, xn1, xn2, t3, t4);
        if (L1LDS)
            dense_level_lds(sPk, 4096u, 32u, xn0, xn1, xn2, t5, t6);
        else
            dense_level(gtab + 4096u, 32u, xn0, xn1, xn2, t5, t6);
        dense_level2_pk(A2, B2, xn0, xn1, xn2, t7, t8);
        hp[p][3][lane] = t3; hp[p][4][lane] = t4;
        hp[p][5][lane] = t5; hp[p][6][lane] = t6;
        hp[p][7][lane] = t7; hp[p][8][lane] = t8;

        // Levels 3+4 from feat buffers (coalesced NT dword loads).
        #pragma unroll
        for (int l = 0; l < 2; ++l) {
            const unsigned pk = __builtin_nontemporal_load(
                feat + (size_t)l * N + gs);
            hp[p][9 + 2 * l][lane]  = bf2f_lo(pk);
            hp[p][10 + 2 * l][lane] = bf2f_hi(pk);
        }
    }

    v2f o2[2];
    o2[0] = mlp_pair(wt, hp[0]);
    o2[1] = mlp_pair(wt, hp[1]);

    #pragma unroll
    for (int k = 0; k < 4; ++k) {
        const int g = base + BLOCK * k;
        if (g < N)
            __builtin_nontemporal_store(o2[k >> 1][k & 1], out + g);
    }
}

extern "C" void kernel_launch(void* const* d_in, const int* in_sizes, int n_in,
                              void* d_out, int out_size, void* d_ws, size_t ws_size,
                              hipStream_t stream) {
    const float* x    = (const float*)d_in[0];
    const float* grid = (const float*)d_in[1];
    const float* W0   = (const float*)d_in[2];
    const float* b0   = (const float*)d_in[3];
    const float* W1   = (const float*)d_in[4];
    const float* b1   = (const float*)d_in[5];
    float* out = (float*)d_out;

    const int N = in_sizes[0] / 3;
    const int blocks1 = (N + 255) / 256;

    const float2* gtab = (const float2*)grid;

    auto align256 = [](size_t v) { return (v + 255) & ~(size_t)255; };
    size_t off = 0;
    const size_t feat_off = off; off += align256((size_t)2 * N * 4);
    const size_t wt_off   = off; off += align256(1089 * 4);
    const size_t pk_off   = off; off += align256(36864 * 4);
    const size_t a2_off   = off; off += align256(262144 * 4);
    const size_t b2_off   = off; off += align256(262144 * 4);
    const size_t p5_off   = off; off += align256(524288 * 4);
    (void)ws_size;

    unsigned* feat   = (unsigned*)((char*)d_ws + feat_off);
    float*    wt     = (float*)((char*)d_ws + wt_off);
    unsigned* packed = (unsigned*)((char*)d_ws + pk_off);
    unsigned* A2     = (unsigned*)((char*)d_ws + a2_off);
    unsigned* B2     = (unsigned*)((char*)d_ws + b2_off);
    unsigned* pk5    = (unsigned*)((char*)d_ws + p5_off);

    // K1: hash level 3 + prep (128 tail blocks: packed01, A2/B2, pk5, wt;
    // all tail streams nontemporal).
    hash3_prep_kernel<<<blocks1 + 128, 256, 0, stream>>>(
        x, gtab, feat + (size_t)0 * N, N, wt, packed, A2, B2, pk5,
        W0, b0, W1, b1);
    // K2: hash level 4 (R13 form, fp32 table).
    hash_level_kernel<<<blocks1, 256, 0, stream>>>(
        x, gtab + 823296u, feat + (size_t)1 * N, 255.0f, N);

    // K3: fused hash5(bf16) + dense + MLP. Tables 4MB, streams all NT.
    const size_t bigShm = 36864u * 4u;           // 147456 B
    const void* bigK =
        reinterpret_cast<const void*>(&fused5_mlp_kernel<1024, true>);
    (void)hipFuncSetAttribute(bigK,
        hipFuncAttributeMaxDynamicSharedMemorySize, (int)bigShm);
    bool big = false;
    hipFuncAttributes fa{};
    if (hipFuncGetAttributes(&fa, bigK) == hipSuccess)
        big = ((size_t)fa.maxDynamicSharedSizeBytes >= bigShm);

    if (big) {
        const int blocksB = (N + 4095) / 4096;   // 1024 thr x 4 pts
        fused5_mlp_kernel<1024, true><<<blocksB, 1024, bigShm, stream>>>(
            x, (const float*)grid, feat, wt, packed, A2, B2, pk5, out, N);
    } else {
        const int blocksF = (N + 1023) / 1024;   // 256 thr x 4 pts
        fused5_mlp_kernel<256, false><<<blocksF, 256, 4096u * 4u, stream>>>(
            x, (const float*)grid, feat, wt, packed, A2, B2, pk5, out, N);
    }
}

// Round 9
// 349.651 us; speedup vs baseline: 1.0997x; 1.0997x over previous
//
#include <hip/hip_runtime.h>

// GridManifoldNetwork, round 22 = R20/R21 fused with PERSISTENT BLOCKS.
// R21 post-mortem: fused FETCH 231MB decomposes as ~75MB LDS-staging
// re-reads (512 blocks x 147KB `packed`, staged at different times, evicted
// between stagings by the 25M-request gather stream) + table refetch +
// unavoidable streams. R21's NT-staging made it WORSE (203us): NT forbids
// L2 serving the re-reads -> HBM-direct every block. Fix is structural:
// 256 grid-stride blocks (1/CU), staging happens ONCE each, simultaneously
// at t=0 while `packed` is L2-hot (~1-2MB HBM total), then 2 point-chunks
// per block. Staging load reverts to CACHED. Streams (x/feat/out) stay NT.
//
// Predicted: fused FETCH <110MB (decisive), dur 202 -> 115-140us, total
// ~280-295us. Falsifier: FETCH drops but dur >=160 -> fusion is
// wall-incompatible beyond cache traffic -> revert to R18 split (308us).
//
// Kept verbatim (proven): R13 hash gather form (hash3/hash4, fp32 tables),
// R11 MLP form, 144KB LDS levels 0+1, A2/B2 level-2 pair tables, bf16 pk5
// (R16: bf16 hash table = same speed, half size), prep-in-tail pattern.
//
// Levels: res=16,32,64,128,256,512; F=2; T=2^19; levels 3..5 hashed,
// & 0x7FFFF. Entry offsets: 0,4096,36864,299008,823296,1347584.

#define HP1 2654435761u
#define HP2 805459861u
#define HMASK ((1u << 19) - 1u)

typedef float v2f __attribute__((ext_vector_type(2)));

static __device__ __forceinline__ unsigned umin_(unsigned a, unsigned b) {
    return a < b ? a : b;
}

// bf16 round-to-nearest-even pack/unpack.
static __device__ __forceinline__ unsigned f2bf(float f) {
    unsigned u = __float_as_uint(f);
    return (u + 0x7fffu + ((u >> 16) & 1u)) >> 16;
}
static __device__ __forceinline__ float bf2f_lo(unsigned p) {
    return __uint_as_float((p & 0xffffu) << 16);
}
static __device__ __forceinline__ float bf2f_hi(unsigned p) {
    return __uint_as_float(p & 0xffff0000u);
}

static __device__ __forceinline__ v2f vmax0(v2f s) {
#if __has_builtin(__builtin_elementwise_max)
    return __builtin_elementwise_max(s, (v2f)0.0f);
#else
    v2f r; r.x = fmaxf(s.x, 0.0f); r.y = fmaxf(s.y, 0.0f); return r;
#endif
}

// NT read of a float2 as two floats (builtin needs scalar types).
static __device__ __forceinline__ void nt_load_f2(
    const float2* __restrict__ p, float& ex, float& ey)
{
    const unsigned long long u =
        __builtin_nontemporal_load((const unsigned long long*)p);
    ex = __uint_as_float((unsigned)u);
    ey = __uint_as_float((unsigned)(u >> 32));
}

// One hashed-level point block: R13 form verbatim. 8 divergent 8B gathers
// from the fp32 float2 table + trilerp + bf16 pack. 72.5us/level proven.
static __device__ __forceinline__ void hash_body(
    const float* __restrict__ x, const float2* __restrict__ tab,
    unsigned* __restrict__ feat, float scale, int N, int bid)
{
    const int gid = bid * 256 + threadIdx.x;
    if (gid >= N) return;

    const float px = __builtin_nontemporal_load(x + 3 * gid + 0);
    const float py = __builtin_nontemporal_load(x + 3 * gid + 1);
    const float pz = __builtin_nontemporal_load(x + 3 * gid + 2);

    const float p0 = fmaf((px + 1.0f) * 0.5f, scale, 0.5f);
    const float p1 = fmaf((py + 1.0f) * 0.5f, scale, 0.5f);
    const float p2 = fmaf((pz + 1.0f) * 0.5f, scale, 0.5f);
    const float g0 = floorf(p0), g1 = floorf(p1), g2 = floorf(p2);
    const float f0 = p0 - g0, f1 = p1 - g1, f2 = p2 - g2;
    const unsigned i0 = (unsigned)g0, i1 = (unsigned)g1, i2 = (unsigned)g2;

    const float wx[2] = {1.0f - f0, f0};
    const float wy[2] = {1.0f - f1, f1};
    const float wz[2] = {1.0f - f2, f2};
    const unsigned hx[2] = {i0, i0 + 1u};
    const unsigned hy[2] = {i1 * HP1, (i1 + 1u) * HP1};
    const unsigned hz[2] = {i2 * HP2, (i2 + 1u) * HP2};

    unsigned idx[8];
    float w[8];
    #pragma unroll
    for (int c = 0; c < 8; ++c) {
        const int bx = c & 1, by = (c >> 1) & 1, bz = (c >> 2) & 1;
        idx[c] = (hx[bx] ^ hy[by] ^ hz[bz]) & HMASK;
        w[c] = wx[bx] * wy[by] * wz[bz];
    }
    float2 v[8];
    #pragma unroll
    for (int c = 0; c < 8; ++c) v[c] = tab[idx[c]];

    float a0 = 0.0f, a1 = 0.0f;
    #pragma unroll
    for (int c = 0; c < 8; ++c) {
        a0 = fmaf(w[c], v[c].x, a0);
        a1 = fmaf(w[c], v[c].y, a1);
    }
    __builtin_nontemporal_store(f2bf(a0) | (f2bf(a1) << 16), feat + gid);
}

// Hash level 3 + all prep folded into 128 tail blocks. Tail streams are
// nontemporal (read once, written once) so they don't evict hash3's table.
__global__ __launch_bounds__(256) void hash3_prep_kernel(
    const float* __restrict__ x, const float2* __restrict__ gtab,
    unsigned* __restrict__ feat0, int N,
    float* __restrict__ wt, unsigned* __restrict__ packed,
    unsigned* __restrict__ A2, unsigned* __restrict__ B2,
    unsigned* __restrict__ pk5,
    const float* __restrict__ W0, const float* __restrict__ b0,
    const float* __restrict__ W1, const float* __restrict__ b1)
{
    const int nh = (int)gridDim.x - 128;
    if ((int)blockIdx.x >= nh) {
        const int pb = (int)blockIdx.x - nh;   // 0..127
        const int stride = 128 * 256;
        for (int t = pb * 256 + threadIdx.x; t < 36864; t += stride) {
            float ex, ey;
            nt_load_f2(gtab + t, ex, ey);
            __builtin_nontemporal_store(f2bf(ex) | (f2bf(ey) << 16),
                                        packed + t);
        }
        const float2* g2 = gtab + 36864u;      // level 2, 64^3 entries
        for (int t = pb * 256 + threadIdx.x; t < 262144; t += stride) {
            float ex, ey;
            nt_load_f2(g2 + t, ex, ey);
            __builtin_nontemporal_store(f2bf(ex) | (f2bf(ey) << 16), A2 + t);
            const int xc = t & 63;
            float nx, ny;
            nt_load_f2(g2 + ((xc == 63) ? t : t + 1), nx, ny);
            __builtin_nontemporal_store(f2bf(nx) | (f2bf(ny) << 16), B2 + t);
        }
        const float2* g5 = gtab + 1347584u;    // hash level 5
        for (int t = pb * 256 + threadIdx.x; t < 524288; t += stride) {
            float ex, ey;
            nt_load_f2(g5 + t, ex, ey);
            __builtin_nontemporal_store(f2bf(ex) | (f2bf(ey) << 16), pk5 + t);
        }
        if (pb == 0) {
            for (int t = threadIdx.x; t < 1024; t += 256) {
                const int j = t >> 4, i = t & 15;
                wt[t] = (i == 15) ? b0[j] : W0[i * 64 + j];
            }
            if (threadIdx.x < 64) wt[1024 + threadIdx.x] = W1[threadIdx.x];
            if (threadIdx.x == 0) wt[1088] = b1[0];
        }
        return;
    }
    hash_body(x, gtab + 299008u, feat0, 127.0f, N, (int)blockIdx.x);
}

__global__ __launch_bounds__(256) void hash_level_kernel(
    const float* __restrict__ x, const float2* __restrict__ tab,
    unsigned* __restrict__ feat, float scale, int N)
{
    hash_body(x, tab, feat, scale, N, (int)blockIdx.x);
}

// Dense trilinear level from global fp32 float2 (level-1 fallback only).
static __device__ __forceinline__ void dense_level(
    const float2* __restrict__ tab, unsigned res,
    float xn0, float xn1, float xn2, float& o0, float& o1)
{
    const float scale = (float)(res - 1);
    const float p0 = fmaf(xn0, scale, 0.5f);
    const float p1 = fmaf(xn1, scale, 0.5f);
    const float p2 = fmaf(xn2, scale, 0.5f);
    const float g0 = floorf(p0), g1 = floorf(p1), g2 = floorf(p2);
    const float f0 = p0 - g0, f1 = p1 - g1, f2 = p2 - g2;
    const unsigned i0 = (unsigned)g0, i1 = (unsigned)g1, i2 = (unsigned)g2;

    const unsigned rm1 = res - 1u;
    const unsigned cx[2] = {umin_(i0, rm1), umin_(i0 + 1u, rm1)};
    const unsigned cy[2] = {umin_(i1, rm1) * res, umin_(i1 + 1u, rm1) * res};
    const unsigned cz[2] = {umin_(i2, rm1) * res * res,
                            umin_(i2 + 1u, rm1) * res * res};
    const float wx[2] = {1.0f - f0, f0};
    const float wy[2] = {1.0f - f1, f1};
    const float wz[2] = {1.0f - f2, f2};

    float a0 = 0.0f, a1 = 0.0f;
    #pragma unroll
    for (int c = 0; c < 8; ++c) {
        const int bx = c & 1, by = (c >> 1) & 1, bz = (c >> 2) & 1;
        const unsigned idx = cx[bx] + cy[by] + cz[bz];
        const float w = wx[bx] * wy[by] * wz[bz];
        const float2 v = tab[idx];
        a0 = fmaf(w, v.x, a0);
        a1 = fmaf(w, v.y, a1);
    }
    o0 = a0;
    o1 = a1;
}

// Dense trilinear level from LDS-resident packed bf16x2 table (R11 form).
static __device__ __forceinline__ void dense_level_lds(
    const unsigned* __restrict__ sPk, unsigned off, unsigned res,
    float xn0, float xn1, float xn2, float& o0, float& o1)
{
    const float scale = (float)(res - 1);
    const float p0 = fmaf(xn0, scale, 0.5f);
    const float p1 = fmaf(xn1, scale, 0.5f);
    const float p2 = fmaf(xn2, scale, 0.5f);
    const float g0 = floorf(p0), g1 = floorf(p1), g2 = floorf(p2);
    const float f0 = p0 - g0, f1 = p1 - g1, f2 = p2 - g2;
    const unsigned i0 = (unsigned)g0, i1 = (unsigned)g1, i2 = (unsigned)g2;

    const unsigned rm1 = res - 1u;
    const unsigned cx[2] = {umin_(i0, rm1), umin_(i0 + 1u, rm1)};
    const unsigned cy[2] = {umin_(i1, rm1) * res, umin_(i1 + 1u, rm1) * res};
    const unsigned cz[2] = {umin_(i2, rm1) * res * res,
                            umin_(i2 + 1u, rm1) * res * res};
    const float wx[2] = {1.0f - f0, f0};
    const float wy[2] = {1.0f - f1, f1};
    const float wz[2] = {1.0f - f2, f2};

    float a0 = 0.0f, a1 = 0.0f;
    #pragma unroll
    for (int c = 0; c < 8; ++c) {
        const int bx = c & 1, by = (c >> 1) & 1, bz = (c >> 2) & 1;
        const unsigned p = sPk[off + cx[bx] + cy[by] + cz[bz]];
        const float w = wx[bx] * wy[by] * wz[bz];
        a0 = fmaf(w, bf2f_lo(p), a0);
        a1 = fmaf(w, bf2f_hi(p), a1);
    }
    o0 = a0;
    o1 = a1;
}

// Dense level 2 (res=64) from packed pair tables (R15-verified dense win).
static __device__ __forceinline__ void dense_level2_pk(
    const unsigned* __restrict__ A2, const unsigned* __restrict__ B2,
    float xn0, float xn1, float xn2, float& o0, float& o1)
{
    const float p0 = fmaf(xn0, 63.0f, 0.5f);
    const float p1 = fmaf(xn1, 63.0f, 0.5f);
    const float p2 = fmaf(xn2, 63.0f, 0.5f);
    const float g0 = floorf(p0), g1 = floorf(p1), g2 = floorf(p2);
    const float f0 = p0 - g0, f1 = p1 - g1, f2 = p2 - g2;
    const unsigned i0 = (unsigned)g0, i1 = (unsigned)g1, i2 = (unsigned)g2;

    const unsigned cx0 = umin_(i0, 63u);
    const unsigned cy[2] = {umin_(i1, 63u) * 64u, umin_(i1 + 1u, 63u) * 64u};
    const unsigned cz[2] = {umin_(i2, 63u) * 4096u,
                            umin_(i2 + 1u, 63u) * 4096u};
    const float wx[2] = {1.0f - f0, f0};
    const float wy[2] = {1.0f - f1, f1};
    const float wz[2] = {1.0f - f2, f2};

    const unsigned* tsel = (cx0 & 1u) ? B2 : A2;
    const unsigned xb = cx0 & ~1u;

    float a0 = 0.0f, a1 = 0.0f;
    #pragma unroll
    for (int c = 0; c < 4; ++c) {
        const int by = c & 1, bz = (c >> 1) & 1;
        const uint2 q = *reinterpret_cast<const uint2*>(
            tsel + xb + cy[by] + cz[bz]);
        const float wyz = wy[by] * wz[bz];
        const float w0 = wyz * wx[0], w1 = wyz * wx[1];
        a0 = fmaf(w0, bf2f_lo(q.x), a0);
        a1 = fmaf(w0, bf2f_hi(q.x), a1);
        a0 = fmaf(w1, bf2f_lo(q.y), a0);
        a1 = fmaf(w1, bf2f_hi(q.y), a1);
    }
    o0 = a0;
    o1 = a1;
}

// Hash level 5 inline from bf16x2 packed table (4B gathers, 2MB resident).
static __device__ __forceinline__ void hash5_pt(
    const unsigned* __restrict__ tab, float xn0, float xn1, float xn2,
    float& o0, float& o1)
{
    const float p0 = fmaf(xn0, 511.0f, 0.5f);
    const float p1 = fmaf(xn1, 511.0f, 0.5f);
    const float p2 = fmaf(xn2, 511.0f, 0.5f);
    const float g0 = floorf(p0), g1 = floorf(p1), g2 = floorf(p2);
    const float f0 = p0 - g0, f1 = p1 - g1, f2 = p2 - g2;
    const unsigned i0 = (unsigned)g0, i1 = (unsigned)g1, i2 = (unsigned)g2;

    const float wx[2] = {1.0f - f0, f0};
    const float wy[2] = {1.0f - f1, f1};
    const float wz[2] = {1.0f - f2, f2};
    const unsigned hx[2] = {i0, i0 + 1u};
    const unsigned hy[2] = {i1 * HP1, (i1 + 1u) * HP1};
    const unsigned hz[2] = {i2 * HP2, (i2 + 1u) * HP2};

    unsigned idx[8];
    float w[8];
    #pragma unroll
    for (int c = 0; c < 8; ++c) {
        const int bx = c & 1, by = (c >> 1) & 1, bz = (c >> 2) & 1;
        idx[c] = (hx[bx] ^ hy[by] ^ hz[bz]) & HMASK;
        w[c] = wx[bx] * wy[by] * wz[bz];
    }
    unsigned v[8];
    #pragma unroll
    for (int c = 0; c < 8; ++c) v[c] = tab[idx[c]];

    float a0 = 0.0f, a1 = 0.0f;
    #pragma unroll
    for (int c = 0; c < 8; ++c) {
        a0 = fmaf(w[c], bf2f_lo(v[c]), a0);
        a1 = fmaf(w[c], bf2f_hi(v[c]), a1);
    }
    o0 = a0;
    o1 = a1;
}

// MLP for one 2-point pair: R11 form verbatim (weights via SMEM pipe,
// v_pk_fma over v2f pairs).
static __device__ __forceinline__ v2f mlp_pair(
    const float* __restrict__ wt, const v2f* __restrict__ hp)
{
    v2f o2 = (v2f)wt[1088];
    #pragma unroll 4
    for (int j = 0; j < 64; ++j) {
        float r[16];
        #pragma unroll
        for (int i = 0; i < 16; ++i)
            r[i] = wt[j * 16 + i];          // uniform -> s_load (SMEM pipe)
        const float w1j = wt[1024 + j];
        v2f s = (v2f)0.0f;
        #pragma unroll
        for (int i = 0; i < 16; ++i)
            s = hp[i] * r[i] + s;            // v_pk_fma_f32
        s = vmax0(s);
        o2 = s * w1j + o2;
    }
    return o2;
}

// FUSED K3: hash level 5 (bf16 table) + dense levels 0/1/2 + MLP.
// PERSISTENT blocks: stage LDS once (cached loads, simultaneous across the
// chip -> L2-hot), then grid-stride over point chunks. 12 random req/pt
// over 4MB resident tables; x/feat/out streams nontemporal.
template<int BLOCK, bool L1LDS>
__global__ __launch_bounds__(BLOCK, 4) void fused5_mlp_kernel(
    const float* __restrict__ x,
    const float* __restrict__ grid,
    const unsigned* __restrict__ feat,   // [2][N] packed bf16x2 (lvl 3,4)
    const float* __restrict__ wt,        // 1089 floats
    const unsigned* __restrict__ packed, // 36864 bf16x2 words (levels 0+1)
    const unsigned* __restrict__ A2,     // level-2 packed (identity)
    const unsigned* __restrict__ B2,     // level-2 packed (x+1, clamped)
    const unsigned* __restrict__ pk5,    // hash level 5, bf16x2 (2MB)
    float* __restrict__ out, int N)
{
    extern __shared__ unsigned sPk[];
    const int tid = threadIdx.x;

    const int nstage = L1LDS ? 36864 : 4096;
    for (int t = tid; t < nstage; t += BLOCK)
        sPk[t] = packed[t];              // cached: L2 serves the replicas
    __syncthreads();

    const float2* gtab = (const float2*)grid;
    const int npb = BLOCK * 4;           // points per block-chunk

    for (int base0 = (int)blockIdx.x * npb; base0 < N;
         base0 += (int)gridDim.x * npb) {
        const int base = base0 + tid;

        // hp[p][i] = {feature i of point 2p, feature i of point 2p+1}
        v2f hp[2][16];

        #pragma unroll
        for (int k = 0; k < 4; ++k) {
            const int g = base + BLOCK * k;
            const int gs = (g < N) ? g : 0;
            const int p = k >> 1, lane = k & 1;

            const float px = __builtin_nontemporal_load(x + 3 * gs + 0);
            const float py = __builtin_nontemporal_load(x + 3 * gs + 1);
            const float pz = __builtin_nontemporal_load(x + 3 * gs + 2);
            const float xn0 = (px + 1.0f) * 0.5f;
            const float xn1 = (py + 1.0f) * 0.5f;
            const float xn2 = (pz + 1.0f) * 0.5f;

            hp[p][0][lane] = px; hp[p][1][lane] = py; hp[p][2][lane] = pz;
            hp[p][15][lane] = 1.0f;

            // Hash level 5 inline (bf16 table, no feat2 round-trip).
            float h5a, h5b;
            hash5_pt(pk5, xn0, xn1, xn2, h5a, h5b);
            hp[p][13][lane] = h5a; hp[p][14][lane] = h5b;

            // Dense levels 0..2.
            float t3, t4, t5, t6, t7, t8;
            dense_level_lds(sPk, 0u, 16u, xn0, xn1, xn2, t3, t4);
            if (L1LDS)
                dense_level_lds(sPk, 4096u, 32u, xn0, xn1, xn2, t5, t6);
            else
                dense_level(gtab + 4096u, 32u, xn0, xn1, xn2, t5, t6);
            dense_level2_pk(A2, B2, xn0, xn1, xn2, t7, t8);
            hp[p][3][lane] = t3; hp[p][4][lane] = t4;
            hp[p][5][lane] = t5; hp[p][6][lane] = t6;
            hp[p][7][lane] = t7; hp[p][8][lane] = t8;

            // Levels 3+4 from feat buffers (coalesced NT dword loads).
            #pragma unroll
            for (int l = 0; l < 2; ++l) {
                const unsigned pk = __builtin_nontemporal_load(
                    feat + (size_t)l * N + gs);
                hp[p][9 + 2 * l][lane]  = bf2f_lo(pk);
                hp[p][10 + 2 * l][lane] = bf2f_hi(pk);
            }
        }

        v2f o2[2];
        o2[0] = mlp_pair(wt, hp[0]);
        o2[1] = mlp_pair(wt, hp[1]);

        #pragma unroll
        for (int k = 0; k < 4; ++k) {
            const int g = base + BLOCK * k;
            if (g < N)
                __builtin_nontemporal_store(o2[k >> 1][k & 1], out + g);
        }
    }
}

extern "C" void kernel_launch(void* const* d_in, const int* in_sizes, int n_in,
                              void* d_out, int out_size, void* d_ws, size_t ws_size,
                              hipStream_t stream) {
    const float* x    = (const float*)d_in[0];
    const float* grid = (const float*)d_in[1];
    const float* W0   = (const float*)d_in[2];
    const float* b0   = (const float*)d_in[3];
    const float* W1   = (const float*)d_in[4];
    const float* b1   = (const float*)d_in[5];
    float* out = (float*)d_out;

    const int N = in_sizes[0] / 3;
    const int blocks1 = (N + 255) / 256;

    const float2* gtab = (const float2*)grid;

    auto align256 = [](size_t v) { return (v + 255) & ~(size_t)255; };
    size_t off = 0;
    const size_t feat_off = off; off += align256((size_t)2 * N * 4);
    const size_t wt_off   = off; off += align256(1089 * 4);
    const size_t pk_off   = off; off += align256(36864 * 4);
    const size_t a2_off   = off; off += align256(262144 * 4);
    const size_t b2_off   = off; off += align256(262144 * 4);
    const size_t p5_off   = off; off += align256(524288 * 4);
    (void)ws_size;

    unsigned* feat   = (unsigned*)((char*)d_ws + feat_off);
    float*    wt     = (float*)((char*)d_ws + wt_off);
    unsigned* packed = (unsigned*)((char*)d_ws + pk_off);
    unsigned* A2     = (unsigned*)((char*)d_ws + a2_off);
    unsigned* B2     = (unsigned*)((char*)d_ws + b2_off);
    unsigned* pk5    = (unsigned*)((char*)d_ws + p5_off);

    // K1: hash level 3 + prep (128 tail blocks: packed01, A2/B2, pk5, wt).
    hash3_prep_kernel<<<blocks1 + 128, 256, 0, stream>>>(
        x, gtab, feat + (size_t)0 * N, N, wt, packed, A2, B2, pk5,
        W0, b0, W1, b1);
    // K2: hash level 4 (R13 form, fp32 table).
    hash_level_kernel<<<blocks1, 256, 0, stream>>>(
        x, gtab + 823296u, feat + (size_t)1 * N, 255.0f, N);

    // K3: fused hash5(bf16) + dense + MLP, persistent blocks (1/CU).
    const size_t bigShm = 36864u * 4u;           // 147456 B
    const void* bigK =
        reinterpret_cast<const void*>(&fused5_mlp_kernel<1024, true>);
    (void)hipFuncSetAttribute(bigK,
        hipFuncAttributeMaxDynamicSharedMemorySize, (int)bigShm);
    bool big = false;
    hipFuncAttributes fa{};
    if (hipFuncGetAttributes(&fa, bigK) == hipSuccess)
        big = ((size_t)fa.maxDynamicSharedSizeBytes >= bigShm);

    if (big) {
        int blocksB = (N + 4095) / 4096;         // 1024 thr x 4 pts
        if (blocksB > 256) blocksB = 256;        // 1 block/CU, grid-stride
        fused5_mlp_kernel<1024, true><<<blocksB, 1024, bigShm, stream>>>(
            x, (const float*)grid, feat, wt, packed, A2, B2, pk5, out, N);
    } else {
        int blocksF = (N + 1023) / 1024;         // 256 thr x 4 pts
        if (blocksF > 2048) blocksF = 2048;      // grid-stride fallback
        fused5_mlp_kernel<256, false><<<blocksF, 256, 4096u * 4u, stream>>>(
            x, (const float*)grid, feat, wt, packed, A2, B2, pk5, out, N);
    }
}

// Round 10
// 306.198 us; speedup vs baseline: 1.2558x; 1.1419x over previous
//
#include <hip/hip_runtime.h>

// GridManifoldNetwork, round 23 = REVERT to best proven composition.
// Fusion arc (R19-R22) closed as FALSIFIED: 190/178/202/168us vs split's
// 157us for the same work. Root cause (final): 144KB-LDS fused kernel caps
// at 16 waves/CU; dependent gather->trilerp->MLP chains at 16 waves run the
// request pipe at 0.15M req/us vs the 0.232M wall the lean 32-wave hash
// kernels sustain (R22 FETCH 194MB, miss rate ~7.5% -> not thrash; latency).
//
// Composition (each piece the best measured of its kind):
//  - hash3+prep / hash4 / hash5: R13 plain 8x8B fp32 gathers (72.5us/level,
//    optimum over 6 request-shaping variants: R15 pair16B=90.6, R16 4B=74,
//    R17 pair8B=79 all worse), prep in 64 tail blocks (R12, -6us).
//  - dense_mlp: R16 body verbatim (83.2us; R18's pipelined form was 84.5 ->
//    pipelining falsified). A2/B2 bf16 level-2 pair tables (95->83 arc),
//    levels 0+1 from 144KB LDS, R11 MLP form (SMEM weights, v_pk_fma).
//
// Model floor: 3x72.5 (request wall: 8 req/pt x 2M / 0.232M req/us,
// invariant across width/residency/count shaping) + 84.5 (34.5 req + 47
// VALU, overlap falsified by R18) ~ 302us. Predicted total ~305-310.
// If confirmed -> roofline next round.
//
// Levels: res=16,32,64,128,256,512; F=2; T=2^19; levels 3..5 hashed,
// & 0x7FFFF. Entry offsets: 0,4096,36864,299008,823296,1347584.

#define HP1 2654435761u
#define HP2 805459861u
#define HMASK ((1u << 19) - 1u)

typedef float v2f __attribute__((ext_vector_type(2)));

static __device__ __forceinline__ unsigned umin_(unsigned a, unsigned b) {
    return a < b ? a : b;
}

// bf16 round-to-nearest-even pack/unpack.
static __device__ __forceinline__ unsigned f2bf(float f) {
    unsigned u = __float_as_uint(f);
    return (u + 0x7fffu + ((u >> 16) & 1u)) >> 16;
}
static __device__ __forceinline__ float bf2f_lo(unsigned p) {
    return __uint_as_float((p & 0xffffu) << 16);
}
static __device__ __forceinline__ float bf2f_hi(unsigned p) {
    return __uint_as_float(p & 0xffff0000u);
}

static __device__ __forceinline__ v2f vmax0(v2f s) {
#if __has_builtin(__builtin_elementwise_max)
    return __builtin_elementwise_max(s, (v2f)0.0f);
#else
    v2f r; r.x = fmaxf(s.x, 0.0f); r.y = fmaxf(s.y, 0.0f); return r;
#endif
}

// One hashed-level point block: R13 form verbatim. 8 divergent 8B gathers
// from the fp32 float2 table + trilerp + bf16 pack. 72.5us/level proven.
static __device__ __forceinline__ void hash_body(
    const float* __restrict__ x, const float2* __restrict__ tab,
    unsigned* __restrict__ feat, float scale, int N, int bid)
{
    const int gid = bid * 256 + threadIdx.x;
    if (gid >= N) return;

    const float px = __builtin_nontemporal_load(x + 3 * gid + 0);
    const float py = __builtin_nontemporal_load(x + 3 * gid + 1);
    const float pz = __builtin_nontemporal_load(x + 3 * gid + 2);

    const float p0 = fmaf((px + 1.0f) * 0.5f, scale, 0.5f);
    const float p1 = fmaf((py + 1.0f) * 0.5f, scale, 0.5f);
    const float p2 = fmaf((pz + 1.0f) * 0.5f, scale, 0.5f);
    const float g0 = floorf(p0), g1 = floorf(p1), g2 = floorf(p2);
    const float f0 = p0 - g0, f1 = p1 - g1, f2 = p2 - g2;
    const unsigned i0 = (unsigned)g0, i1 = (unsigned)g1, i2 = (unsigned)g2;

    const float wx[2] = {1.0f - f0, f0};
    const float wy[2] = {1.0f - f1, f1};
    const float wz[2] = {1.0f - f2, f2};
    const unsigned hx[2] = {i0, i0 + 1u};
    const unsigned hy[2] = {i1 * HP1, (i1 + 1u) * HP1};
    const unsigned hz[2] = {i2 * HP2, (i2 + 1u) * HP2};

    unsigned idx[8];
    float w[8];
    #pragma unroll
    for (int c = 0; c < 8; ++c) {
        const int bx = c & 1, by = (c >> 1) & 1, bz = (c >> 2) & 1;
        idx[c] = (hx[bx] ^ hy[by] ^ hz[bz]) & HMASK;
        w[c] = wx[bx] * wy[by] * wz[bz];
    }
    float2 v[8];
    #pragma unroll
    for (int c = 0; c < 8; ++c) v[c] = tab[idx[c]];

    float a0 = 0.0f, a1 = 0.0f;
    #pragma unroll
    for (int c = 0; c < 8; ++c) {
        a0 = fmaf(w[c], v[c].x, a0);
        a1 = fmaf(w[c], v[c].y, a1);
    }
    __builtin_nontemporal_store(f2bf(a0) | (f2bf(a1) << 16), feat + gid);
}

// Hash level 3 + all prep folded into 64 tail blocks (R12-verified):
// tail builds packed01 (LDS source), A2/B2 level-2 pair tables, wt.
__global__ __launch_bounds__(256) void hash3_prep_kernel(
    const float* __restrict__ x, const float2* __restrict__ gtab,
    unsigned* __restrict__ feat0, int N,
    float* __restrict__ wt, unsigned* __restrict__ packed,
    unsigned* __restrict__ A2, unsigned* __restrict__ B2,
    const float* __restrict__ W0, const float* __restrict__ b0,
    const float* __restrict__ W1, const float* __restrict__ b1)
{
    const int nh = (int)gridDim.x - 64;
    if ((int)blockIdx.x >= nh) {
        const int pb = (int)blockIdx.x - nh;   // 0..63
        for (int t = pb * 256 + threadIdx.x; t < 36864; t += 64 * 256) {
            const float2 e = gtab[t];
            packed[t] = f2bf(e.x) | (f2bf(e.y) << 16);
        }
        const float2* g2 = gtab + 36864u;      // level 2, 64^3 entries
        for (int t = pb * 256 + threadIdx.x; t < 262144; t += 64 * 256) {
            const float2 e = g2[t];
            A2[t] = f2bf(e.x) | (f2bf(e.y) << 16);
            const int xc = t & 63;
            const float2 en = g2[(xc == 63) ? t : t + 1];
            B2[t] = f2bf(en.x) | (f2bf(en.y) << 16);
        }
        if (pb == 0) {
            for (int t = threadIdx.x; t < 1024; t += 256) {
                const int j = t >> 4, i = t & 15;
                wt[t] = (i == 15) ? b0[j] : W0[i * 64 + j];
            }
            if (threadIdx.x < 64) wt[1024 + threadIdx.x] = W1[threadIdx.x];
            if (threadIdx.x == 0) wt[1088] = b1[0];
        }
        return;
    }
    hash_body(x, gtab + 299008u, feat0, 127.0f, N, (int)blockIdx.x);
}

__global__ __launch_bounds__(256) void hash_level_kernel(
    const float* __restrict__ x, const float2* __restrict__ tab,
    unsigned* __restrict__ feat, float scale, int N)
{
    hash_body(x, tab, feat, scale, N, (int)blockIdx.x);
}

// Dense trilinear level from global fp32 float2 (level-1 fallback only).
static __device__ __forceinline__ void dense_level(
    const float2* __restrict__ tab, unsigned res,
    float xn0, float xn1, float xn2, float& o0, float& o1)
{
    const float scale = (float)(res - 1);
    const float p0 = fmaf(xn0, scale, 0.5f);
    const float p1 = fmaf(xn1, scale, 0.5f);
    const float p2 = fmaf(xn2, scale, 0.5f);
    const float g0 = floorf(p0), g1 = floorf(p1), g2 = floorf(p2);
    const float f0 = p0 - g0, f1 = p1 - g1, f2 = p2 - g2;
    const unsigned i0 = (unsigned)g0, i1 = (unsigned)g1, i2 = (unsigned)g2;

    const unsigned rm1 = res - 1u;
    const unsigned cx[2] = {umin_(i0, rm1), umin_(i0 + 1u, rm1)};
    const unsigned cy[2] = {umin_(i1, rm1) * res, umin_(i1 + 1u, rm1) * res};
    const unsigned cz[2] = {umin_(i2, rm1) * res * res,
                            umin_(i2 + 1u, rm1) * res * res};
    const float wx[2] = {1.0f - f0, f0};
    const float wy[2] = {1.0f - f1, f1};
    const float wz[2] = {1.0f - f2, f2};

    float a0 = 0.0f, a1 = 0.0f;
    #pragma unroll
    for (int c = 0; c < 8; ++c) {
        const int bx = c & 1, by = (c >> 1) & 1, bz = (c >> 2) & 1;
        const unsigned idx = cx[bx] + cy[by] + cz[bz];
        const float w = wx[bx] * wy[by] * wz[bz];
        const float2 v = tab[idx];
        a0 = fmaf(w, v.x, a0);
        a1 = fmaf(w, v.y, a1);
    }
    o0 = a0;
    o1 = a1;
}

// Dense level 2 (res=64) from packed pair tables: every x-corner pair is
// one aligned 8B load (A2 even base-x, B2 shifted copy for odd; clamp
// baked into B2). R15/R16-verified dense win (95 -> 83us arc).
static __device__ __forceinline__ void dense_level2_pk(
    const unsigned* __restrict__ A2, const unsigned* __restrict__ B2,
    float xn0, float xn1, float xn2, float& o0, float& o1)
{
    const float p0 = fmaf(xn0, 63.0f, 0.5f);
    const float p1 = fmaf(xn1, 63.0f, 0.5f);
    const float p2 = fmaf(xn2, 63.0f, 0.5f);
    const float g0 = floorf(p0), g1 = floorf(p1), g2 = floorf(p2);
    const float f0 = p0 - g0, f1 = p1 - g1, f2 = p2 - g2;
    const unsigned i0 = (unsigned)g0, i1 = (unsigned)g1, i2 = (unsigned)g2;

    const unsigned cx0 = umin_(i0, 63u);
    const unsigned cy[2] = {umin_(i1, 63u) * 64u, umin_(i1 + 1u, 63u) * 64u};
    const unsigned cz[2] = {umin_(i2, 63u) * 4096u,
                            umin_(i2 + 1u, 63u) * 4096u};
    const float wx[2] = {1.0f - f0, f0};
    const float wy[2] = {1.0f - f1, f1};
    const float wz[2] = {1.0f - f2, f2};

    const unsigned* tsel = (cx0 & 1u) ? B2 : A2;
    const unsigned xb = cx0 & ~1u;

    float a0 = 0.0f, a1 = 0.0f;
    #pragma unroll
    for (int c = 0; c < 4; ++c) {
        const int by = c & 1, bz = (c >> 1) & 1;
        const uint2 q = *reinterpret_cast<const uint2*>(
            tsel + xb + cy[by] + cz[bz]);
        const float wyz = wy[by] * wz[bz];
        const float w0 = wyz * wx[0], w1 = wyz * wx[1];
        a0 = fmaf(w0, bf2f_lo(q.x), a0);
        a1 = fmaf(w0, bf2f_hi(q.x), a1);
        a0 = fmaf(w1, bf2f_lo(q.y), a0);
        a1 = fmaf(w1, bf2f_hi(q.y), a1);
    }
    o0 = a0;
    o1 = a1;
}

// Dense trilinear level from LDS-resident packed bf16x2 table (R11 form).
static __device__ __forceinline__ void dense_level_lds(
    const unsigned* __restrict__ sPk, unsigned off, unsigned res,
    float xn0, float xn1, float xn2, float& o0, float& o1)
{
    const float scale = (float)(res - 1);
    const float p0 = fmaf(xn0, scale, 0.5f);
    const float p1 = fmaf(xn1, scale, 0.5f);
    const float p2 = fmaf(xn2, scale, 0.5f);
    const float g0 = floorf(p0), g1 = floorf(p1), g2 = floorf(p2);
    const float f0 = p0 - g0, f1 = p1 - g1, f2 = p2 - g2;
    const unsigned i0 = (unsigned)g0, i1 = (unsigned)g1, i2 = (unsigned)g2;

    const unsigned rm1 = res - 1u;
    const unsigned cx[2] = {umin_(i0, rm1), umin_(i0 + 1u, rm1)};
    const unsigned cy[2] = {umin_(i1, rm1) * res, umin_(i1 + 1u, rm1) * res};
    const unsigned cz[2] = {umin_(i2, rm1) * res * res,
                            umin_(i2 + 1u, rm1) * res * res};
    const float wx[2] = {1.0f - f0, f0};
    const float wy[2] = {1.0f - f1, f1};
    const float wz[2] = {1.0f - f2, f2};

    float a0 = 0.0f, a1 = 0.0f;
    #pragma unroll
    for (int c = 0; c < 8; ++c) {
        const int bx = c & 1, by = (c >> 1) & 1, bz = (c >> 2) & 1;
        const unsigned p = sPk[off + cx[bx] + cy[by] + cz[bz]];
        const float w = wx[bx] * wy[by] * wz[bz];
        a0 = fmaf(w, bf2f_lo(p), a0);
        a1 = fmaf(w, bf2f_hi(p), a1);
    }
    o0 = a0;
    o1 = a1;
}

// Dense levels + MLP, 4 points/thread (R16 body verbatim, 83.2us proven).
// L1LDS=true: levels 0+1 from 144KB LDS; false: level 0 only. Level 2 via
// packed pair tables. Weights via SMEM pipe; MLP over 2-pt v2f pairs.
template<int BLOCK, bool L1LDS>
__global__ __launch_bounds__(BLOCK, 4) void dense_mlp_kernel(
    const float* __restrict__ x,
    const float* __restrict__ grid,
    const unsigned* __restrict__ feat,   // [3][N] packed bf16x2
    const float* __restrict__ wt,        // 1089 floats
    const unsigned* __restrict__ packed, // 36864 bf16x2 words (levels 0+1)
    const unsigned* __restrict__ A2,     // level-2 packed (identity)
    const unsigned* __restrict__ B2,     // level-2 packed (x+1, clamped)
    float* __restrict__ out, int N)
{
    extern __shared__ unsigned sPk[];
    const int tid = threadIdx.x;

    const int nstage = L1LDS ? 36864 : 4096;
    for (int t = tid; t < nstage; t += BLOCK)
        sPk[t] = packed[t];
    __syncthreads();

    const int base = blockIdx.x * (BLOCK * 4) + tid;
    const float2* gtab = (const float2*)grid;

    // hp[p][i] = {feature i of point 2p, feature i of point 2p+1}
    v2f hp[2][16];

    #pragma unroll
    for (int k = 0; k < 4; ++k) {
        const int g = base + BLOCK * k;
        const int gs = (g < N) ? g : 0;
        const int p = k >> 1, lane = k & 1;

        const float px = __builtin_nontemporal_load(x + 3 * gs + 0);
        const float py = __builtin_nontemporal_load(x + 3 * gs + 1);
        const float pz = __builtin_nontemporal_load(x + 3 * gs + 2);
        const float xn0 = (px + 1.0f) * 0.5f;
        const float xn1 = (py + 1.0f) * 0.5f;
        const float xn2 = (pz + 1.0f) * 0.5f;

        hp[p][0][lane] = px; hp[p][1][lane] = py; hp[p][2][lane] = pz;
        hp[p][15][lane] = 1.0f;

        float t3, t4, t5, t6, t7, t8;
        dense_level_lds(sPk, 0u, 16u, xn0, xn1, xn2, t3, t4);
        if (L1LDS)
            dense_level_lds(sPk, 4096u, 32u, xn0, xn1, xn2, t5, t6);
        else
            dense_level(gtab + 4096u, 32u, xn0, xn1, xn2, t5, t6);
        dense_level2_pk(A2, B2, xn0, xn1, xn2, t7, t8);
        hp[p][3][lane] = t3; hp[p][4][lane] = t4;
        hp[p][5][lane] = t5; hp[p][6][lane] = t6;
        hp[p][7][lane] = t7; hp[p][8][lane] = t8;

        #pragma unroll
        for (int l = 0; l < 3; ++l) {
            const unsigned pk = __builtin_nontemporal_load(
                feat + (size_t)l * N + gs);
            hp[p][9 + 2 * l][lane]  = bf2f_lo(pk);
            hp[p][10 + 2 * l][lane] = bf2f_hi(pk);
        }
    }

    // MLP: out = relu(h @ W0 + b0) @ W1 + b1 (bias folded via h[15]=1).
    const float b1v = wt[1088];
    v2f o2[2];
    o2[0] = (v2f)b1v; o2[1] = (v2f)b1v;

    #pragma unroll 4
    for (int j = 0; j < 64; ++j) {
        float r[16];
        #pragma unroll
        for (int i = 0; i < 16; ++i)
            r[i] = wt[j * 16 + i];          // uniform -> s_load (SMEM pipe)
        const float w1j = wt[1024 + j];
        #pragma unroll
        for (int p = 0; p < 2; ++p) {
            v2f s = (v2f)0.0f;
            #pragma unroll
            for (int i = 0; i < 16; ++i)
                s = hp[p][i] * r[i] + s;     // v_pk_fma_f32
            s = vmax0(s);
            o2[p] = s * w1j + o2[p];
        }
    }

    #pragma unroll
    for (int k = 0; k < 4; ++k) {
        const int g = base + BLOCK * k;
        if (g < N)
            __builtin_nontemporal_store(o2[k >> 1][k & 1], out + g);
    }
}

extern "C" void kernel_launch(void* const* d_in, const int* in_sizes, int n_in,
                              void* d_out, int out_size, void* d_ws, size_t ws_size,
                              hipStream_t stream) {
    const float* x    = (const float*)d_in[0];
    const float* grid = (const float*)d_in[1];
    const float* W0   = (const float*)d_in[2];
    const float* b0   = (const float*)d_in[3];
    const float* W1   = (const float*)d_in[4];
    const float* b1   = (const float*)d_in[5];
    float* out = (float*)d_out;

    const int N = in_sizes[0] / 3;
    const int blocks1 = (N + 255) / 256;

    const float2* gtab = (const float2*)grid;

    auto align256 = [](size_t v) { return (v + 255) & ~(size_t)255; };
    size_t off = 0;
    const size_t feat_off = off; off += align256((size_t)3 * N * 4);
    const size_t wt_off   = off; off += align256(1089 * 4);
    const size_t pk_off   = off; off += align256(36864 * 4);
    const size_t a2_off   = off; off += align256(262144 * 4);
    const size_t b2_off   = off; off += align256(262144 * 4);
    (void)ws_size;

    unsigned* feat   = (unsigned*)((char*)d_ws + feat_off);
    float*    wt     = (float*)((char*)d_ws + wt_off);
    unsigned* packed = (unsigned*)((char*)d_ws + pk_off);
    unsigned* A2     = (unsigned*)((char*)d_ws + a2_off);
    unsigned* B2     = (unsigned*)((char*)d_ws + b2_off);

    // Hash level 3 + prep (64 tail blocks: packed01, A2/B2, wt).
    hash3_prep_kernel<<<blocks1 + 64, 256, 0, stream>>>(
        x, gtab, feat + (size_t)0 * N, N, wt, packed, A2, B2, W0, b0, W1, b1);
    hash_level_kernel<<<blocks1, 256, 0, stream>>>(
        x, gtab + 823296u, feat + (size_t)1 * N, 255.0f, N);
    hash_level_kernel<<<blocks1, 256, 0, stream>>>(
        x, gtab + 1347584u, feat + (size_t)2 * N, 511.0f, N);

    // Gate the 144KB-LDS path on what the runtime actually permits
    // (host-side queries: deterministic, graph-capture-safe).
    const size_t bigShm = 36864u * 4u;           // 147456 B
    const void* bigK =
        reinterpret_cast<const void*>(&dense_mlp_kernel<1024, true>);
    (void)hipFuncSetAttribute(bigK,
        hipFuncAttributeMaxDynamicSharedMemorySize, (int)bigShm);
    bool big = false;
    hipFuncAttributes fa{};
    if (hipFuncGetAttributes(&fa, bigK) == hipSuccess)
        big = ((size_t)fa.maxDynamicSharedSizeBytes >= bigShm);

    if (big) {
        const int blocksB = (N + 4095) / 4096;   // 1024 thr x 4 pts
        dense_mlp_kernel<1024, true><<<blocksB, 1024, bigShm, stream>>>(
            x, (const float*)grid, feat, wt, packed, A2, B2, out, N);
    } else {
        const int blocksF = (N + 1023) / 1024;   // 256 thr x 4 pts
        dense_mlp_kernel<256, false><<<blocksF, 256, 4096u * 4u, stream>>>(
            x, (const float*)grid, feat, wt, packed, A2, B2, out, N);
    }
}